// Round 9
// baseline (123.237 us; speedup 1.0000x reference)
//
#include <hip/hip_runtime.h>

// Conv2d 3x3 VALID (NCHW/OIHW, fp32), fp16 MFMA, v5 "resident-X".
// Block = (image n, output row-pair): 220 sp (pad 224) x 128 cout.
// Fill LDS ONCE: 4 input rows x 112 cols x 64 ch as fp16, [row][col][ch]
// ch-minor, slot-XOR swizzle (ch-octet ^ (col&7)) -> conflict-free b128 reads.
// Then 9 shifts x 4 k-steps = 144 MFMA/wave with NO barriers (shift = LDS offset).
// v3/v4-verified frag & store mappings retained.

typedef __attribute__((ext_vector_type(8)))  _Float16 f16x8;
typedef __attribute__((ext_vector_type(16))) float    f32x16;

constexpr int C_IN = 64, H = 112, W = 112;
constexpr int COUT = 128, OH = 110, OW = 110;
constexpr int NIMG = 32;
constexpr int KTOT = C_IN * 9;            // 576
constexpr int OSP  = OH * OW;             // 12100
constexpr int IMG_STRIDE = C_IN * H * W;
constexpr int CH_STRIDE  = H * W;         // 12544
constexpr int ROWS = 4;                   // input rows per tile (2 out + 2 halo)
constexpr int NRP  = OH / 2;              // 55 row-pairs
constexpr int NWG  = NIMG * NRP;          // 1760 blocks (%8==0)

__device__ __forceinline__ uint pkrtz_u32(float lo, float hi) {
    union { __fp16 __attribute__((ext_vector_type(2))) h; uint u; } c;
    c.h = __builtin_amdgcn_cvt_pkrtz(lo, hi);
    return c.u;
}

// A16[((s*8+o)*COUT + cout)*8 + j] = (f16)Kw[cout][(o*8+j)*9 + s]   (v4-verified)
__global__ void prep_a(const float* __restrict__ Kw, _Float16* __restrict__ A16) {
    int idx = blockIdx.x * 256 + threadIdx.x;
    if (idx >= COUT * KTOT) return;
    int cout = idx / KTOT, k = idx - cout * KTOT;
    int c = k / 9, s = k - c * 9;
    int o = c >> 3, j = c & 7;
    A16[((size_t)(s * 8 + o) * COUT + cout) * 8 + j] = (_Float16)Kw[idx];
}

__global__ __launch_bounds__(512, 4)
void conv_resx_f16(const float* __restrict__ X,
                   const _Float16* __restrict__ A16,
                   float* __restrict__ Out)
{
    __shared__ __align__(16) _Float16 Xs[ROWS * W * C_IN];   // 57344 B

    const int t = threadIdx.x;

    // XCD swizzle (1760 % 8 == 0 -> simple bijective)
    const int bid = (blockIdx.x & 7) * (NWG >> 3) + (blockIdx.x >> 3);
    const int n   = bid / NRP;
    const int rp  = bid - n * NRP;
    const int oh0 = rp * 2;

    const float* Xn = X + (size_t)n * IMG_STRIDE + (size_t)oh0 * W;

    // ---- fill: 1792 tasks = 224 w-pairs(4 rows x 56) x 8 ch-groups ----
    if (t < 448) {
#pragma unroll
        for (int q = 0; q < 4; q++) {
            const int tau = q * 448 + t;
            const int cg  = tau / 224;           // 0..7
            const int wpr = tau - cg * 224;      // 0..223
            const int row = wpr / 56;            // 0..3
            const int wcl = (wpr - row * 56) * 2;
            const float* src = Xn + (size_t)(cg * 8) * CH_STRIDE + row * W + wcl;
            float2 v[8];
#pragma unroll
            for (int j = 0; j < 8; j++)
                v[j] = *reinterpret_cast<const float2*>(src + (size_t)j * CH_STRIDE);
            union { uint u[4]; f16x8 h; } p0, p1;
#pragma unroll
            for (int p = 0; p < 4; p++) {
                p0.u[p] = pkrtz_u32(v[2 * p].x, v[2 * p + 1].x);
                p1.u[p] = pkrtz_u32(v[2 * p].y, v[2 * p + 1].y);
            }
            const int a0 = (row * W + wcl)     * C_IN + ((cg ^ (wcl & 7)) << 3);
            const int a1 = (row * W + wcl + 1) * C_IN + ((cg ^ ((wcl + 1) & 7)) << 3);
            *reinterpret_cast<f16x8*>(&Xs[a0]) = p0.h;
            *reinterpret_cast<f16x8*>(&Xs[a1]) = p1.h;
        }
    }

    // ---- compute mapping: 8 waves = 4 cout-quarters x 2 sp-halves x 4 frags ----
    const int lane  = t & 63;
    const int wv    = t >> 6;
    const int cq    = wv & 3;
    const int sh    = wv >> 2;
    const int frow  = lane & 31;
    const int khalf = lane >> 5;

    int bbase[4], owv[4];
#pragma unroll
    for (int i = 0; i < 4; i++) {
        int spl = (sh * 4 + i) * 32 + frow;      // 0..255 (>=220 dead)
        int s2  = (spl < 220) ? spl : 0;         // clamp dead lanes to safe reads
        int orow = (s2 >= 110) ? 1 : 0;
        int ow   = s2 - orow * 110;
        bbase[i] = (orow * W + ow) * C_IN;
        owv[i]   = ow;
    }

    f32x16 acc[4];
#pragma unroll
    for (int i = 0; i < 4; i++)
#pragma unroll
        for (int e = 0; e < 16; e++) acc[i][e] = 0.f;

    __syncthreads();   // X tile resident; no further barriers

    // ---- 9 shifts x 4 k-steps, all offsets compile-time ----
#pragma unroll
    for (int s = 0; s < 9; s++) {
        const int kh = s / 3, kw = s % 3;
        const int soff = (kh * W + kw) * C_IN;
#pragma unroll
        for (int kk = 0; kk < 4; kk++) {
            const int oct = kk * 2;  // + khalf per-lane
            const f16x8 a = *reinterpret_cast<const f16x8*>(
                &A16[((size_t)((s * 8 + oct + khalf) * COUT) + cq * 32 + frow) * 8]);
#pragma unroll
            for (int i = 0; i < 4; i++) {
                const int slot = ((oct + khalf) ^ ((owv[i] + kw) & 7)) << 3;
                const f16x8 b = *reinterpret_cast<const f16x8*>(
                    &Xs[bbase[i] + soff + slot]);
                acc[i] = __builtin_amdgcn_mfma_f32_32x32x16_f16(a, b, acc[i], 0, 0, 0);
            }
        }
    }

    // ---- store (v3-verified): D col=frow, cout row=(reg&3)+8*(reg>>2)+4*khalf ----
    float* On = Out + (size_t)n * (COUT * (size_t)OSP) + (size_t)(cq * 32 + 4 * khalf) * OSP;
#pragma unroll
    for (int i = 0; i < 4; i++) {
        const int spl = (sh * 4 + i) * 32 + frow;
        if (spl < 220) {
            const int orow = (spl >= 110) ? 1 : 0;
            const int ow   = spl - orow * 110;
            float* Ob = On + (size_t)(oh0 + orow) * OW + ow;
#pragma unroll
            for (int reg = 0; reg < 16; reg++) {
                const int crow = (reg & 3) + 8 * (reg >> 2);
                Ob[(size_t)crow * OSP] = acc[i][reg];
            }
        }
    }
}

extern "C" void kernel_launch(void* const* d_in, const int* in_sizes, int n_in,
                              void* d_out, int out_size, void* d_ws, size_t ws_size,
                              hipStream_t stream) {
    const float* X  = (const float*)d_in[0];
    const float* Kw = (const float*)d_in[1];
    float* Out = (float*)d_out;
    _Float16* A16 = (_Float16*)d_ws;    // 147456 B

    prep_a<<<(COUT * KTOT + 255) / 256, 256, 0, stream>>>(Kw, A16);
    conv_resx_f16<<<NWG, 512, 0, stream>>>(X, A16, Out);
}